// Round 10
// baseline (102.508 us; speedup 1.0000x reference)
//
#include <hip/hip_runtime.h>

#define ALPHA 0.2f

typedef __attribute__((ext_vector_type(8))) short short8v;
typedef __attribute__((ext_vector_type(4))) float f32x4;

__device__ __forceinline__ unsigned cvt_pk_bf16(float a, float b) {
  unsigned d;
  asm("v_cvt_pk_bf16_f32 %0, %1, %2" : "=v"(d) : "v"(a), "v"(b));
  return d;   // lo16 = bf16(a), hi16 = bf16(b)
}

// ------------------------------------------------------------------
// K1: h = x@W  -> hT (bf16, [64][8192]);  s1 = h@a1, s2 = h@a2 (fp32)
// ------------------------------------------------------------------
__global__ __launch_bounds__(256) void k1_proj(
    const float* __restrict__ x, const float* __restrict__ W,
    const float* __restrict__ avec,
    short* __restrict__ hT, float* __restrict__ s1, float* __restrict__ s2) {
  __shared__ float xl[32 * 132];
  __shared__ float Wl[128 * 64];
  const int t   = threadIdx.x;
  const int rb  = blockIdx.x;
  const int row = t >> 3;
  const int fg  = t & 7;
  float acc[8];
#pragma unroll
  for (int e = 0; e < 8; e++) acc[e] = 0.f;

  for (int kc = 0; kc < 4; kc++) {
#pragma unroll
    for (int u = 0; u < 4; u++) {
      int lin = t + u * 256;
      int r = lin >> 5, c4 = lin & 31;
      float4 v = *(const float4*)(x + (size_t)(rb * 32 + r) * 512 + kc * 128 + c4 * 4);
      *(float4*)(xl + r * 132 + c4 * 4) = v;
    }
#pragma unroll
    for (int u = 0; u < 8; u++) {
      int lin = t + u * 256;
      int r = lin >> 4, c4 = lin & 15;
      float4 v = *(const float4*)(W + (size_t)(kc * 128 + r) * 64 + c4 * 4);
      *(float4*)(Wl + r * 64 + c4 * 4) = v;
    }
    __syncthreads();
#pragma unroll 8
    for (int k = 0; k < 128; k++) {
      float xv = xl[row * 132 + k];
      float4 w0 = *(const float4*)(Wl + k * 64 + fg * 8);
      float4 w1 = *(const float4*)(Wl + k * 64 + fg * 8 + 4);
      acc[0] = fmaf(xv, w0.x, acc[0]); acc[1] = fmaf(xv, w0.y, acc[1]);
      acc[2] = fmaf(xv, w0.z, acc[2]); acc[3] = fmaf(xv, w0.w, acc[3]);
      acc[4] = fmaf(xv, w1.x, acc[4]); acc[5] = fmaf(xv, w1.y, acc[5]);
      acc[6] = fmaf(xv, w1.z, acc[6]); acc[7] = fmaf(xv, w1.w, acc[7]);
    }
    __syncthreads();
  }

  float p1 = 0.f, p2 = 0.f;
#pragma unroll
  for (int e = 0; e < 8; e++) {
    p1 = fmaf(acc[e], avec[fg * 8 + e], p1);
    p2 = fmaf(acc[e], avec[64 + fg * 8 + e], p2);
  }
  p1 += __shfl_xor(p1, 1, 64); p1 += __shfl_xor(p1, 2, 64); p1 += __shfl_xor(p1, 4, 64);
  p2 += __shfl_xor(p2, 1, 64); p2 += __shfl_xor(p2, 2, 64); p2 += __shfl_xor(p2, 4, 64);
  const int gi = rb * 32 + row;
  if (fg == 0) { s1[gi] = p1; s2[gi] = p2; }
#pragma unroll
  for (int e = 0; e < 8; e++) {
    union { float f; unsigned u; } v; v.f = acc[e];
    unsigned rr = v.u + 0x7fffu + ((v.u >> 16) & 1u);
    hT[(size_t)(fg * 8 + e) * 8192 + gi] = (short)(rr >> 16);
  }
}

// ------------------------------------------------------------------
// K2 v10: identical to v9 EXCEPT block mapping is rb-MAJOR:
// concurrent blocks = same 64-row group x all 16 j-splits -> their
// union is 64 rows x 32 KB CONTIGUOUS (2 MB dense) -> DRAM channel
// streams become page-dense instead of 2KB-island-hopping.
// ------------------------------------------------------------------
__global__ __launch_bounds__(256, 2) void k2_attn(
    const float* __restrict__ adj, const short* __restrict__ hT,
    const float* __restrict__ s1, const float* __restrict__ s2,
    float* __restrict__ num, float* __restrict__ den) {
  __shared__ short hP[32768];        // 64 KB: [f=64][col=512] swizzled
  __shared__ short Pl[8192];         // 16 KB: 4 waves x [16][128] swizzled
  const int t    = threadIdx.x;
  const int wvi  = t >> 6;
  const int l    = t & 63;
  const int lq   = l >> 4;
  const int lr   = l & 15;
  const int rb   = blockIdx.x >> 4;   // rb-MAJOR (the experiment)
  const int ks   = blockIdx.x & 15;
  const int r0   = rb << 6;
  const int j0   = ks << 9;          // JSPAN = 512

  // ---- 1) small loads first (oldest in queue)
  float  s1own = s1[r0 + wvi * 16 + lr];
  float4 s2A4  = *(const float4*)(s2 + j0 + l * 4);
  float4 s2B4  = *(const float4*)(s2 + j0 + 256 + l * 4);

  // ---- 2) hP stage loads (pre-swizzled source)
  short8v sv[16];
#pragma unroll
  for (int r = 0; r < 16; r++) {
    const int d    = r * 4096 + t * 16;
    const int frow = d >> 10;
    const int lcb  = (d & 1023) ^ ((frow & 7) << 4);
    sv[r] = *(const short8v*)(hT + (size_t)frow * 8192 + j0 + (lcb >> 1));
  }

  // ---- 3) ALL adj for this wave: 16 rows x 2 KB (two float4 groups)
  const float* ar = adj + (size_t)(r0 + wvi * 16) * 8192 + j0 + l * 4;
  float4 A0,A1,A2,A3,A4,A5,A6,A7,A8,A9,A10,A11,A12,A13,A14,A15;
  float4 B0,B1,B2,B3,B4,B5,B6,B7,B8,B9,B10,B11,B12,B13,B14,B15;
  A0  = *(const float4*)(ar);              B0  = *(const float4*)(ar + 256);
  A1  = *(const float4*)(ar + 1 * 8192);   B1  = *(const float4*)(ar + 1 * 8192 + 256);
  A2  = *(const float4*)(ar + 2 * 8192);   B2  = *(const float4*)(ar + 2 * 8192 + 256);
  A3  = *(const float4*)(ar + 3 * 8192);   B3  = *(const float4*)(ar + 3 * 8192 + 256);
  A4  = *(const float4*)(ar + 4 * 8192);   B4  = *(const float4*)(ar + 4 * 8192 + 256);
  A5  = *(const float4*)(ar + 5 * 8192);   B5  = *(const float4*)(ar + 5 * 8192 + 256);
  A6  = *(const float4*)(ar + 6 * 8192);   B6  = *(const float4*)(ar + 6 * 8192 + 256);
  A7  = *(const float4*)(ar + 7 * 8192);   B7  = *(const float4*)(ar + 7 * 8192 + 256);
  A8  = *(const float4*)(ar + 8 * 8192);   B8  = *(const float4*)(ar + 8 * 8192 + 256);
  A9  = *(const float4*)(ar + 9 * 8192);   B9  = *(const float4*)(ar + 9 * 8192 + 256);
  A10 = *(const float4*)(ar + 10 * 8192);  B10 = *(const float4*)(ar + 10 * 8192 + 256);
  A11 = *(const float4*)(ar + 11 * 8192);  B11 = *(const float4*)(ar + 11 * 8192 + 256);
  A12 = *(const float4*)(ar + 12 * 8192);  B12 = *(const float4*)(ar + 12 * 8192 + 256);
  A13 = *(const float4*)(ar + 13 * 8192);  B13 = *(const float4*)(ar + 13 * 8192 + 256);
  A14 = *(const float4*)(ar + 14 * 8192);  B14 = *(const float4*)(ar + 14 * 8192 + 256);
  A15 = *(const float4*)(ar + 15 * 8192);  B15 = *(const float4*)(ar + 15 * 8192 + 256);

  // ---- 4) write hP, barrier (drains ALL vmem: adj now in registers)
#pragma unroll
  for (int r = 0; r < 16; r++)
    *(short8v*)((char*)hP + r * 4096 + t * 16) = sv[r];
  __syncthreads();

  float s1r[16];
#pragma unroll
  for (int i = 0; i < 16; i++) s1r[i] = __shfl(s1own, i, 64);

  float denom_p[16];
#pragma unroll
  for (int i = 0; i < 16; i++) denom_p[i] = 0.f;
  f32x4 acc[4];
#pragma unroll
  for (int fb = 0; fb < 4; fb++) acc[fb] = (f32x4){0.f, 0.f, 0.f, 0.f};

  char* Pw = (char*)Pl + wvi * 4096;
  unsigned pk0[16], pk1[16];

#define EXPROW4(I, AV, S2V) do {                                              \
    float z0 = s1r[I] + S2V.x; z0 = fmaxf(z0, ALPHA * z0) * AV.x;             \
    float z1 = s1r[I] + S2V.y; z1 = fmaxf(z1, ALPHA * z1) * AV.y;             \
    float z2 = s1r[I] + S2V.z; z2 = fmaxf(z2, ALPHA * z2) * AV.z;             \
    float z3 = s1r[I] + S2V.w; z3 = fmaxf(z3, ALPHA * z3) * AV.w;             \
    float w0 = __expf(z0), w1 = __expf(z1), w2 = __expf(z2), w3 = __expf(z3); \
    denom_p[I] += (w0 + w1) + (w2 + w3);                                      \
    pk0[I] = cvt_pk_bf16(w0, w1); pk1[I] = cvt_pk_bf16(w2, w3);               \
  } while (0)

#define PWRITE(HALF) do {                                                     \
    if ((l >> 5) == (HALF)) {                                                 \
      const int cb = (l & 31) * 8;                                            \
      _Pragma("unroll")                                                       \
      for (int i2 = 0; i2 < 16; i2++) {                                       \
        uint2 pv; pv.x = pk0[i2]; pv.y = pk1[i2];                             \
        *(uint2*)(Pw + (((i2 << 8) + cb) ^ ((i2 & 7) << 4))) = pv;            \
      }                                                                       \
    }                                                                         \
  } while (0)

#define MFMACHUNK(CL) do {                                                    \
    __builtin_amdgcn_s_setprio(1);                                            \
    _Pragma("unroll")                                                         \
    for (int kk = 0; kk < 4; kk++) {                                          \
      const int ab = ((lr << 8) + (kk << 6) + (lq << 4)) ^ ((lr & 7) << 4);   \
      const short8v au = *(const short8v*)(Pw + ab);                          \
      _Pragma("unroll")                                                       \
      for (int fb = 0; fb < 4; fb++) {                                        \
        const int fr = fb * 16 + lr;                                          \
        const int bb = ((fr << 10) + ((CL) << 8) + (kk << 6) + (lq << 4))     \
                       ^ ((fr & 7) << 4);                                     \
        const short8v bu = *(const short8v*)((char*)hP + bb);                 \
        acc[fb] = __builtin_amdgcn_mfma_f32_16x16x32_bf16(au, bu,             \
                                                          acc[fb], 0, 0, 0); \
      }                                                                       \
    }                                                                         \
    __builtin_amdgcn_s_setprio(0);                                            \
  } while (0)

  // ---- group 0 (cols 0..255): lanes<32 hold chunk 0, lanes>=32 chunk 1
  EXPROW4(0, A0, s2A4);   EXPROW4(1, A1, s2A4);   EXPROW4(2, A2, s2A4);
  EXPROW4(3, A3, s2A4);   EXPROW4(4, A4, s2A4);   EXPROW4(5, A5, s2A4);
  EXPROW4(6, A6, s2A4);   EXPROW4(7, A7, s2A4);   EXPROW4(8, A8, s2A4);
  EXPROW4(9, A9, s2A4);   EXPROW4(10, A10, s2A4); EXPROW4(11, A11, s2A4);
  EXPROW4(12, A12, s2A4); EXPROW4(13, A13, s2A4); EXPROW4(14, A14, s2A4);
  EXPROW4(15, A15, s2A4);
  PWRITE(0); MFMACHUNK(0);
  PWRITE(1); MFMACHUNK(1);

  // ---- group 1 (cols 256..511): chunks 2, 3
  EXPROW4(0, B0, s2B4);   EXPROW4(1, B1, s2B4);   EXPROW4(2, B2, s2B4);
  EXPROW4(3, B3, s2B4);   EXPROW4(4, B4, s2B4);   EXPROW4(5, B5, s2B4);
  EXPROW4(6, B6, s2B4);   EXPROW4(7, B7, s2B4);   EXPROW4(8, B8, s2B4);
  EXPROW4(9, B9, s2B4);   EXPROW4(10, B10, s2B4); EXPROW4(11, B11, s2B4);
  EXPROW4(12, B12, s2B4); EXPROW4(13, B13, s2B4); EXPROW4(14, B14, s2B4);
  EXPROW4(15, B15, s2B4);
  PWRITE(0); MFMACHUNK(2);
  PWRITE(1); MFMACHUNK(3);

#undef EXPROW4
#undef PWRITE
#undef MFMACHUNK

  // ---- epilogue: partial denominators and numerators
#pragma unroll
  for (int i = 0; i < 16; i++) {
    float d = denom_p[i];
    d += __shfl_xor(d, 1, 64); d += __shfl_xor(d, 2, 64);
    d += __shfl_xor(d, 4, 64); d += __shfl_xor(d, 8, 64);
    d += __shfl_xor(d, 16, 64); d += __shfl_xor(d, 32, 64);
    if (l == 0) den[(size_t)ks * 8192 + r0 + wvi * 16 + i] = d;
  }
  float* np = num + (size_t)ks * 524288;
#pragma unroll
  for (int fb = 0; fb < 4; fb++)
#pragma unroll
    for (int r = 0; r < 4; r++)
      np[(size_t)(r0 + wvi * 16 + lq * 4 + r) * 64 + fb * 16 + lr] = acc[fb][r];
}

// ------------------------------------------------------------------
// K3: out = elu( sum_ks num / sum_ks den ),  KS = 16
// ------------------------------------------------------------------
__global__ __launch_bounds__(256) void k3_norm(
    const float* __restrict__ num, const float* __restrict__ den,
    float* __restrict__ out) {
  const int idx = blockIdx.x * 256 + threadIdx.x;   // 0..524287
  const int row = idx >> 6;
  float n = 0.f, d = 0.f;
#pragma unroll
  for (int ksi = 0; ksi < 16; ksi++) {
    n += num[(size_t)ksi * 524288 + idx];
    d += den[ksi * 8192 + row];
  }
  float v = n / d;
  out[idx] = v > 0.f ? v : (__expf(v) - 1.f);
}

extern "C" void kernel_launch(void* const* d_in, const int* in_sizes, int n_in,
                              void* d_out, int out_size, void* d_ws, size_t ws_size,
                              hipStream_t stream) {
  const float* x   = (const float*)d_in[0];
  const float* adj = (const float*)d_in[1];
  const float* W   = (const float*)d_in[2];
  const float* av  = (const float*)d_in[3];
  float* out = (float*)d_out;
  char* ws = (char*)d_ws;

  short* hT  = (short*)ws;                                 // 1 MB
  float* s1  = (float*)(ws + (1 << 20));                   // 32 KB
  float* s2  = (float*)(ws + (1 << 20) + 32768);           // 32 KB
  float* num = (float*)(ws + (1 << 20) + 65536);           // 16 x 2 MB
  float* den = num + 16u * 524288u;                        // 16 x 32 KB

  hipLaunchKernelGGL(k1_proj, dim3(256), dim3(256), 0, stream, x, W, av, hT, s1, s2);
  hipLaunchKernelGGL(k2_attn, dim3(2048), dim3(256), 0, stream,
                     adj, hT, s1, s2, num, den);
  hipLaunchKernelGGL(k3_norm, dim3(2048), dim3(256), 0, stream, num, den, out);
}

// Round 11
// 90.846 us; speedup vs baseline: 1.1284x; 1.1284x over previous
//
#include <hip/hip_runtime.h>

#define ALPHA 0.2f

typedef __attribute__((ext_vector_type(8))) short short8v;
typedef __attribute__((ext_vector_type(4))) float f32x4;

__device__ __forceinline__ unsigned cvt_pk_bf16(float a, float b) {
  unsigned d;
  asm("v_cvt_pk_bf16_f32 %0, %1, %2" : "=v"(d) : "v"(a), "v"(b));
  return d;   // lo16 = bf16(a), hi16 = bf16(b)
}

#define GLOAD_LDS16(gp, lp)                                                   \
  __builtin_amdgcn_global_load_lds(                                           \
      (const __attribute__((address_space(1))) unsigned int*)(gp),            \
      (__attribute__((address_space(3))) unsigned int*)(lp), 16, 0, 0)

// ------------------------------------------------------------------
// K1: h = x@W -> hT (bf16 [64][8192]); s1,s2; zeroes num (atomic target).
// ------------------------------------------------------------------
__global__ __launch_bounds__(256) void k1_proj(
    const float* __restrict__ x, const float* __restrict__ W,
    const float* __restrict__ avec,
    short* __restrict__ hT, float* __restrict__ s1, float* __restrict__ s2,
    float* __restrict__ num) {
  __shared__ float xl[32 * 132];
  __shared__ float Wl[128 * 64];
  const int t   = threadIdx.x;
  const int rb  = blockIdx.x;
  const int row = t >> 3;
  const int fg  = t & 7;

  // zero this block's num slice (2048 floats)
  {
    float4 z = {0.f, 0.f, 0.f, 0.f};
    *(float4*)(num + rb * 2048 + t * 8)     = z;
    *(float4*)(num + rb * 2048 + t * 8 + 4) = z;
  }

  float acc[8];
#pragma unroll
  for (int e = 0; e < 8; e++) acc[e] = 0.f;

  for (int kc = 0; kc < 4; kc++) {
#pragma unroll
    for (int u = 0; u < 4; u++) {
      int lin = t + u * 256;
      int r = lin >> 5, c4 = lin & 31;
      float4 v = *(const float4*)(x + (size_t)(rb * 32 + r) * 512 + kc * 128 + c4 * 4);
      *(float4*)(xl + r * 132 + c4 * 4) = v;
    }
#pragma unroll
    for (int u = 0; u < 8; u++) {
      int lin = t + u * 256;
      int r = lin >> 4, c4 = lin & 15;
      float4 v = *(const float4*)(W + (size_t)(kc * 128 + r) * 64 + c4 * 4);
      *(float4*)(Wl + r * 64 + c4 * 4) = v;
    }
    __syncthreads();
#pragma unroll 8
    for (int k = 0; k < 128; k++) {
      float xv = xl[row * 132 + k];
      float4 w0 = *(const float4*)(Wl + k * 64 + fg * 8);
      float4 w1 = *(const float4*)(Wl + k * 64 + fg * 8 + 4);
      acc[0] = fmaf(xv, w0.x, acc[0]); acc[1] = fmaf(xv, w0.y, acc[1]);
      acc[2] = fmaf(xv, w0.z, acc[2]); acc[3] = fmaf(xv, w0.w, acc[3]);
      acc[4] = fmaf(xv, w1.x, acc[4]); acc[5] = fmaf(xv, w1.y, acc[5]);
      acc[6] = fmaf(xv, w1.z, acc[6]); acc[7] = fmaf(xv, w1.w, acc[7]);
    }
    __syncthreads();
  }

  float p1 = 0.f, p2 = 0.f;
#pragma unroll
  for (int e = 0; e < 8; e++) {
    p1 = fmaf(acc[e], avec[fg * 8 + e], p1);
    p2 = fmaf(acc[e], avec[64 + fg * 8 + e], p2);
  }
  p1 += __shfl_xor(p1, 1, 64); p1 += __shfl_xor(p1, 2, 64); p1 += __shfl_xor(p1, 4, 64);
  p2 += __shfl_xor(p2, 1, 64); p2 += __shfl_xor(p2, 2, 64); p2 += __shfl_xor(p2, 4, 64);
  const int gi = rb * 32 + row;
  if (fg == 0) { s1[gi] = p1; s2[gi] = p2; }
#pragma unroll
  for (int e = 0; e < 8; e++) {
    union { float f; unsigned u; } v; v.f = acc[e];
    unsigned rr = v.u + 0x7fffu + ((v.u >> 16) & 1u);
    hT[(size_t)(fg * 8 + e) * 8192 + gi] = (short)(rr >> 16);
  }
}

// ------------------------------------------------------------------
// K2 v11: mem/compute overlap restored.
//  - prologue: s-loads, hP via global_load_lds(16), adj G0 (cols 0..255).
//  - __syncthreads drains those (needed immediately anyway).
//  - adj G1 issued AFTER barrier -> streams during G0 exp+MFMA.
//  - num accumulated via atomicAdd into single 2MB buffer (k1-zeroed).
// ------------------------------------------------------------------
__global__ __launch_bounds__(256, 2) void k2_attn(
    const float* __restrict__ adj, const short* __restrict__ hT,
    const float* __restrict__ s1, const float* __restrict__ s2,
    float* __restrict__ num, float* __restrict__ den) {
  __shared__ short hP[32768];        // 64 KB: [f=64][col=512] swizzled
  __shared__ short Pl[8192];         // 16 KB: 4 waves x [16][128] swizzled
  const int t    = threadIdx.x;
  const int wvi  = t >> 6;
  const int l    = t & 63;
  const int lq   = l >> 4;
  const int lr   = l & 15;
  const int rb   = blockIdx.x & 127;
  const int ks   = blockIdx.x >> 7;
  const int r0   = rb << 6;
  const int j0   = ks << 9;          // JSPAN = 512

  // ---- small loads first
  float  s1own = s1[r0 + wvi * 16 + lr];
  float4 s2A4  = *(const float4*)(s2 + j0 + l * 4);
  float4 s2B4  = *(const float4*)(s2 + j0 + 256 + l * 4);

  // ---- hP stage via global_load_lds (dest = uniform base + lane*16)
#pragma unroll
  for (int r = 0; r < 16; r++) {
    const int d    = r * 4096 + t * 16;
    const int frow = d >> 10;
    const int lcb  = (d & 1023) ^ ((frow & 7) << 4);
    GLOAD_LDS16(hT + (size_t)frow * 8192 + j0 + (lcb >> 1), (char*)hP + d);
  }

  // ---- adj group 0 (cols 0..255): 16 rows x 1 KB
  const float* ar = adj + (size_t)(r0 + wvi * 16) * 8192 + j0 + l * 4;
  float4 A0,A1,A2,A3,A4,A5,A6,A7,A8,A9,A10,A11,A12,A13,A14,A15;
  A0  = *(const float4*)(ar);
  A1  = *(const float4*)(ar + 1 * 8192);
  A2  = *(const float4*)(ar + 2 * 8192);
  A3  = *(const float4*)(ar + 3 * 8192);
  A4  = *(const float4*)(ar + 4 * 8192);
  A5  = *(const float4*)(ar + 5 * 8192);
  A6  = *(const float4*)(ar + 6 * 8192);
  A7  = *(const float4*)(ar + 7 * 8192);
  A8  = *(const float4*)(ar + 8 * 8192);
  A9  = *(const float4*)(ar + 9 * 8192);
  A10 = *(const float4*)(ar + 10 * 8192);
  A11 = *(const float4*)(ar + 11 * 8192);
  A12 = *(const float4*)(ar + 12 * 8192);
  A13 = *(const float4*)(ar + 13 * 8192);
  A14 = *(const float4*)(ar + 14 * 8192);
  A15 = *(const float4*)(ar + 15 * 8192);

  __syncthreads();                   // drains hP + G0 (both needed now)
  __builtin_amdgcn_sched_barrier(0); // pin: G1 loads stay AFTER the barrier

  // ---- adj group 1 issued NOW: streams during G0 compute
  float4 B0,B1,B2,B3,B4,B5,B6,B7,B8,B9,B10,B11,B12,B13,B14,B15;
  B0  = *(const float4*)(ar + 256);
  B1  = *(const float4*)(ar + 1 * 8192 + 256);
  B2  = *(const float4*)(ar + 2 * 8192 + 256);
  B3  = *(const float4*)(ar + 3 * 8192 + 256);
  B4  = *(const float4*)(ar + 4 * 8192 + 256);
  B5  = *(const float4*)(ar + 5 * 8192 + 256);
  B6  = *(const float4*)(ar + 6 * 8192 + 256);
  B7  = *(const float4*)(ar + 7 * 8192 + 256);
  B8  = *(const float4*)(ar + 8 * 8192 + 256);
  B9  = *(const float4*)(ar + 9 * 8192 + 256);
  B10 = *(const float4*)(ar + 10 * 8192 + 256);
  B11 = *(const float4*)(ar + 11 * 8192 + 256);
  B12 = *(const float4*)(ar + 12 * 8192 + 256);
  B13 = *(const float4*)(ar + 13 * 8192 + 256);
  B14 = *(const float4*)(ar + 14 * 8192 + 256);
  B15 = *(const float4*)(ar + 15 * 8192 + 256);

  float s1r[16];
#pragma unroll
  for (int i = 0; i < 16; i++) s1r[i] = __shfl(s1own, i, 64);

  float denom_p[16];
#pragma unroll
  for (int i = 0; i < 16; i++) denom_p[i] = 0.f;
  f32x4 acc[4];
#pragma unroll
  for (int fb = 0; fb < 4; fb++) acc[fb] = (f32x4){0.f, 0.f, 0.f, 0.f};

  char* Pw = (char*)Pl + wvi * 4096;
  unsigned pk0[16], pk1[16];

#define EXPROW4(I, AV, S2V) do {                                              \
    float z0 = s1r[I] + S2V.x; z0 = fmaxf(z0, ALPHA * z0) * AV.x;             \
    float z1 = s1r[I] + S2V.y; z1 = fmaxf(z1, ALPHA * z1) * AV.y;             \
    float z2 = s1r[I] + S2V.z; z2 = fmaxf(z2, ALPHA * z2) * AV.z;             \
    float z3 = s1r[I] + S2V.w; z3 = fmaxf(z3, ALPHA * z3) * AV.w;             \
    float w0 = __expf(z0), w1 = __expf(z1), w2 = __expf(z2), w3 = __expf(z3); \
    denom_p[I] += (w0 + w1) + (w2 + w3);                                      \
    pk0[I] = cvt_pk_bf16(w0, w1); pk1[I] = cvt_pk_bf16(w2, w3);               \
  } while (0)

#define PWRITE(HALF) do {                                                     \
    if ((l >> 5) == (HALF)) {                                                 \
      const int cb = (l & 31) * 8;                                            \
      _Pragma("unroll")                                                       \
      for (int i2 = 0; i2 < 16; i2++) {                                       \
        uint2 pv; pv.x = pk0[i2]; pv.y = pk1[i2];                             \
        *(uint2*)(Pw + (((i2 << 8) + cb) ^ ((i2 & 7) << 4))) = pv;            \
      }                                                                       \
    }                                                                         \
  } while (0)

#define MFMACHUNK(CL) do {                                                    \
    __builtin_amdgcn_s_setprio(1);                                            \
    _Pragma("unroll")                                                         \
    for (int kk = 0; kk < 4; kk++) {                                          \
      const int ab = ((lr << 8) + (kk << 6) + (lq << 4)) ^ ((lr & 7) << 4);   \
      const short8v au = *(const short8v*)(Pw + ab);                          \
      _Pragma("unroll")                                                       \
      for (int fb = 0; fb < 4; fb++) {                                        \
        const int fr = fb * 16 + lr;                                          \
        const int bb = ((fr << 10) + ((CL) << 8) + (kk << 6) + (lq << 4))     \
                       ^ ((fr & 7) << 4);                                     \
        const short8v bu = *(const short8v*)((char*)hP + bb);                 \
        acc[fb] = __builtin_amdgcn_mfma_f32_16x16x32_bf16(au, bu,             \
                                                          acc[fb], 0, 0, 0); \
      }                                                                       \
    }                                                                         \
    __builtin_amdgcn_s_setprio(0);                                            \
  } while (0)

  // ---- group 0 (cols 0..255) while G1 streams
  EXPROW4(0, A0, s2A4);   EXPROW4(1, A1, s2A4);   EXPROW4(2, A2, s2A4);
  EXPROW4(3, A3, s2A4);   EXPROW4(4, A4, s2A4);   EXPROW4(5, A5, s2A4);
  EXPROW4(6, A6, s2A4);   EXPROW4(7, A7, s2A4);   EXPROW4(8, A8, s2A4);
  EXPROW4(9, A9, s2A4);   EXPROW4(10, A10, s2A4); EXPROW4(11, A11, s2A4);
  EXPROW4(12, A12, s2A4); EXPROW4(13, A13, s2A4); EXPROW4(14, A14, s2A4);
  EXPROW4(15, A15, s2A4);
  PWRITE(0); MFMACHUNK(0);
  PWRITE(1); MFMACHUNK(1);

  // ---- group 1 (cols 256..511)
  EXPROW4(0, B0, s2B4);   EXPROW4(1, B1, s2B4);   EXPROW4(2, B2, s2B4);
  EXPROW4(3, B3, s2B4);   EXPROW4(4, B4, s2B4);   EXPROW4(5, B5, s2B4);
  EXPROW4(6, B6, s2B4);   EXPROW4(7, B7, s2B4);   EXPROW4(8, B8, s2B4);
  EXPROW4(9, B9, s2B4);   EXPROW4(10, B10, s2B4); EXPROW4(11, B11, s2B4);
  EXPROW4(12, B12, s2B4); EXPROW4(13, B13, s2B4); EXPROW4(14, B14, s2B4);
  EXPROW4(15, B15, s2B4);
  PWRITE(0); MFMACHUNK(2);
  PWRITE(1); MFMACHUNK(3);

#undef EXPROW4
#undef PWRITE
#undef MFMACHUNK

  // ---- epilogue
#pragma unroll
  for (int i = 0; i < 16; i++) {
    float d = denom_p[i];
    d += __shfl_xor(d, 1, 64); d += __shfl_xor(d, 2, 64);
    d += __shfl_xor(d, 4, 64); d += __shfl_xor(d, 8, 64);
    d += __shfl_xor(d, 16, 64); d += __shfl_xor(d, 32, 64);
    if (l == 0) den[(size_t)ks * 8192 + r0 + wvi * 16 + i] = d;
  }
#pragma unroll
  for (int fb = 0; fb < 4; fb++)
#pragma unroll
    for (int r = 0; r < 4; r++)
      atomicAdd(&num[(size_t)(r0 + wvi * 16 + lq * 4 + r) * 64 + fb * 16 + lr],
                acc[fb][r]);
}

// ------------------------------------------------------------------
// K3: out = elu( num / sum_ks den )
// ------------------------------------------------------------------
__global__ __launch_bounds__(256) void k3_norm(
    const float* __restrict__ num, const float* __restrict__ den,
    float* __restrict__ out) {
  const int idx = blockIdx.x * 256 + threadIdx.x;   // 0..524287
  const int row = idx >> 6;
  float d = 0.f;
#pragma unroll
  for (int ksi = 0; ksi < 16; ksi++) d += den[ksi * 8192 + row];
  float v = num[idx] / d;
  out[idx] = v > 0.f ? v : (__expf(v) - 1.f);
}

extern "C" void kernel_launch(void* const* d_in, const int* in_sizes, int n_in,
                              void* d_out, int out_size, void* d_ws, size_t ws_size,
                              hipStream_t stream) {
  const float* x   = (const float*)d_in[0];
  const float* adj = (const float*)d_in[1];
  const float* W   = (const float*)d_in[2];
  const float* av  = (const float*)d_in[3];
  float* out = (float*)d_out;
  char* ws = (char*)d_ws;

  short* hT  = (short*)ws;                                 // 1 MB
  float* s1  = (float*)(ws + (1 << 20));                   // 32 KB
  float* s2  = (float*)(ws + (1 << 20) + 32768);           // 32 KB
  float* num = (float*)(ws + (1 << 20) + 65536);           // 2 MB (atomic)
  float* den = num + 524288u;                              // 16 x 32 KB

  hipLaunchKernelGGL(k1_proj, dim3(256), dim3(256), 0, stream,
                     x, W, av, hT, s1, s2, num);
  hipLaunchKernelGGL(k2_attn, dim3(2048), dim3(256), 0, stream,
                     adj, hT, s1, s2, num, den);
  hipLaunchKernelGGL(k3_norm, dim3(2048), dim3(256), 0, stream, num, den, out);
}